// Round 15
// baseline (1070.571 us; speedup 1.0000x reference)
//
#include <hip/hip_runtime.h>

// CriterionSA: CAM + grid-PAM + CKA loss.
// GEMMs in split-bf16 MFMA (hi/lo, 3 MFMAs: hh+hl+lh); cam_energy plain bf16
// (softmax saturated). Grams via MFMA split-bf16; fp32 acc -> fp64 atomics.
// CKA fp64, 26 parallel blocks.
// R15: 2-blocks/CU co-residency for ax_k and pam_pv_k: 512 thr, 8 waves of
// 64x64 (acc[4][4]), <=128 regs via __launch_bounds__(512,4), 48KB LDS.
// pam_pv j-split: block jh reads P rows [jh*128,+128) only and writes its
// out-tile into those same rows as flat [256][128] (fixed bijection ->
// gram invariant; no cross-block race; no extra ws).
// ws layout (floats): buf0[26214400] | buf1[26214400] | G[13312 doubles]
// required ws = 209,821,696 bytes (~200.1 MiB) -- same as rounds 1-14.

typedef short bf16x8 __attribute__((ext_vector_type(8)));
typedef float f32x4 __attribute__((ext_vector_type(4)));

constexpr int BB = 16;    // batch
constexpr int CH = 256;   // channels
constexpr int HW = 6400;  // 80*80
constexpr int IMW = 80;

__device__ __forceinline__ int lds_off(int row, int half, int k2) {
  return row * 128 + ((((half << 6)) | k2) ^ ((row & 7) << 4));
}

__device__ __forceinline__ bf16x8 frag_ld(const char* base, int row, int half, int lane) {
  int off = row * 128 + ((((half << 6)) | ((lane >> 4) << 4)) ^ ((lane & 7) << 4));
  return *(const bf16x8*)(base + off);
}

__device__ __forceinline__ void cvt2(float x, unsigned short& h, unsigned short& l) {
  unsigned u = __float_as_uint(x);
  h = (unsigned short)(u >> 16);                       // truncated hi
  float r = x - __uint_as_float(u & 0xffff0000u);
  l = (unsigned short)(__float_as_uint(r) >> 16);      // truncated residual
}

__device__ __forceinline__ void cvt4(float4 v, ushort4& h, ushort4& l) {
  cvt2(v.x, h.x, l.x); cvt2(v.y, h.y, l.y);
  cvt2(v.z, h.z, l.z); cvt2(v.w, h.w, l.w);
}

__device__ __forceinline__ void cvt8(float4 v0, float4 v1, bf16x8& hi, bf16x8& lo) {
  unsigned short h, l;
  cvt2(v0.x, h, l); hi[0] = (short)h; lo[0] = (short)l;
  cvt2(v0.y, h, l); hi[1] = (short)h; lo[1] = (short)l;
  cvt2(v0.z, h, l); hi[2] = (short)h; lo[2] = (short)l;
  cvt2(v0.w, h, l); hi[3] = (short)h; lo[3] = (short)l;
  cvt2(v1.x, h, l); hi[4] = (short)h; lo[4] = (short)l;
  cvt2(v1.y, h, l); hi[5] = (short)h; lo[5] = (short)l;
  cvt2(v1.z, h, l); hi[6] = (short)h; lo[6] = (short)l;
  cvt2(v1.w, h, l); hi[7] = (short)h; lo[7] = (short)l;
}

__device__ __forceinline__ unsigned short bf_rnd(float x) {
  unsigned u = __float_as_uint(x);
  return (unsigned short)((u + 0x8000u) >> 16);
}

// ---------------------------------------------------------------- CAM energy
// Partial E[kc][t][b] = X(:,kslice) X(:,kslice)^T, kc=0..7 (K=800 each,
// 12 x 64 + zero-padded 32 tail). Grid = 256 blocks, 1024 thr (16 waves of
// 64x64 -> acc[4][4]). One LDS panel is both MFMA operands. Double-buffered.
__global__ __launch_bounds__(1024) void cam_energy_k(const float* __restrict__ fS,
                                                     const float* __restrict__ fT,
                                                     float* __restrict__ part) {
  const int kc = blockIdx.x, b = blockIdx.y, t = blockIdx.z;
  const float* X = (t ? fT : fS) + (size_t)b * CH * HW;
  __shared__ unsigned short lds[2 * 256 * 64];  // 2 x 32 KB panels
  const int tid = threadIdx.x, lane = tid & 63, w = tid >> 6;
  const int wr = w >> 2, wc = w & 3;            // 4x4 waves -> 64x64 each
  const int r0 = tid >> 2, kq = tid & 3;        // staging: 4 float4/thread
  const int half = kq >> 1, k2b = (kq & 1) * 32;
  const float* Xr = X + (size_t)r0 * HW + kc * 800 + kq * 16;
  f32x4 acc[4][4] = {};
  float4 v[4];
#pragma unroll
  for (int q = 0; q < 4; ++q) v[q] = *(const float4*)(Xr + q * 4);
  for (int it = 0; it < 13; ++it) {
    char* pb = (char*)lds + (it & 1) * 32768;
#pragma unroll
    for (int q = 0; q < 4; ++q) {
      ushort4 u;
      u.x = bf_rnd(v[q].x); u.y = bf_rnd(v[q].y);
      u.z = bf_rnd(v[q].z); u.w = bf_rnd(v[q].w);
      *(ushort4*)(pb + lds_off(r0, half, k2b + q * 8)) = u;
    }
    __syncthreads();
    float4 nv[4];
    if (it < 12) {
      const int nk = (it + 1) * 64;
      if (nk + kq * 16 < 800) {
        const float* Xn = Xr + nk;
#pragma unroll
        for (int q = 0; q < 4; ++q) nv[q] = *(const float4*)(Xn + q * 4);
      } else {
#pragma unroll
        for (int q = 0; q < 4; ++q) nv[q] = make_float4(0.f, 0.f, 0.f, 0.f);
      }
    }
#pragma unroll
    for (int h = 0; h < 2; ++h) {
      bf16x8 bh[4];
#pragma unroll
      for (int n = 0; n < 4; ++n)
        bh[n] = frag_ld(pb, wc * 64 + n * 16 + (lane & 15), h, lane);
#pragma unroll
      for (int m = 0; m < 4; ++m) {
        bf16x8 a = frag_ld(pb, wr * 64 + m * 16 + (lane & 15), h, lane);
#pragma unroll
        for (int n = 0; n < 4; ++n)
          acc[m][n] = __builtin_amdgcn_mfma_f32_16x16x32_bf16(a, bh[n], acc[m][n], 0, 0, 0);
      }
    }
#pragma unroll
    for (int q = 0; q < 4; ++q) v[q] = nv[q];
  }
  float* Eb = part + (((size_t)kc * 2 + t) * BB + b) * 65536;
#pragma unroll
  for (int m = 0; m < 4; ++m)
#pragma unroll
    for (int n = 0; n < 4; ++n) {
      int row = wr * 64 + m * 16 + ((lane >> 4) << 2);
      int col = wc * 64 + n * 16 + (lane & 15);
#pragma unroll
      for (int r2 = 0; r2 < 4; ++r2)
        Eb[(size_t)(row + r2) * 256 + col] = acc[m][n][r2];
    }
}

// ------------------------------------------------------------- CAM softmax
// attn = exp(rowmin - sum_p partE[p]) / rowsum, written into partial 0.
__global__ __launch_bounds__(64) void cam_softmax_k(float* __restrict__ part) {
  const int c = blockIdx.x, b = blockIdx.y, t = blockIdx.z;
  const size_t base = (((size_t)t * BB + b) * CH + c) * CH;
  const int lane = threadIdx.x;
  float4 x = make_float4(0.f, 0.f, 0.f, 0.f);
#pragma unroll
  for (int p = 0; p < 8; ++p) {
    float4 y = ((const float4*)(part + (size_t)p * 2097152 + base))[lane];
    x.x += y.x; x.y += y.y; x.z += y.z; x.w += y.w;
  }
  float mn = fminf(fminf(x.x, x.y), fminf(x.z, x.w));
  for (int o = 32; o; o >>= 1) mn = fminf(mn, __shfl_xor(mn, o));
  float4 p4;
  p4.x = __expf(mn - x.x); p4.y = __expf(mn - x.y);
  p4.z = __expf(mn - x.z); p4.w = __expf(mn - x.w);
  float s = (p4.x + p4.y) + (p4.z + p4.w);
  for (int o = 32; o; o >>= 1) s += __shfl_xor(s, o);
  const float inv = 1.0f / s;
  p4.x *= inv; p4.y *= inv; p4.z *= inv; p4.w *= inv;
  ((float4*)(part + base))[lane] = p4;
}

// ----------------------------------------------------- A(256x256) @ X GEMM
// MODE 0 (cam_out): OUT[c][n] = g*sum_d A[c][d] X[d][n] + X[c][n]
// MODE 1 (pam_V):   OUT[d][n] = sum_c Wv[d][c] X[c][n] + bv[d]
// R15: 512 thr, 8 waves (4x2 of 64x64 -> acc[4][4]); tile M=256 x N=128;
// single-buffer 48KB LDS, <=128 regs -> 2 blocks/CU co-resident.
template <int MODE>
__global__ __launch_bounds__(512, 4) void ax_k(const float* __restrict__ Abase, int Astride,
                                               const float* __restrict__ X,
                                               float* __restrict__ OUT,
                                               const float* __restrict__ bvec,
                                               const float* __restrict__ gsc) {
  const int nt = blockIdx.x;
  const int b = blockIdx.y;
  const float* A = Abase + (size_t)b * Astride;
  const float* Xb = X + (size_t)b * CH * HW;
  float* OUTb = OUT + (size_t)b * CH * HW;
  const int nbase = nt * 128;
  __shared__ unsigned short lds[(256 + 128) * 64];  // A 32KB + B 16KB
  char* Ab = (char*)lds;
  char* Bb = (char*)lds + 32768;
  const int tid = threadIdx.x, lane = tid & 63, w = tid >> 6;
  const int wr = w >> 1, wc = w & 1;             // 4x2 waves -> 64x64 each
  const int r0a = tid >> 1, kqa = tid & 1;       // A: rows 0-255, 16 k each
  const int n_r = tid & 127, kg = tid >> 7;      // B: row + 8-c group
  const float* Xcol = Xb + nbase + n_r;
  f32x4 acc[4][4] = {};
  float4 ra[4];
  float vb8[8];
#pragma unroll
  for (int q = 0; q < 4; ++q)
    ra[q] = *(const float4*)(A + (size_t)r0a * 256 + kqa * 16 + q * 4);
#pragma unroll
  for (int e = 0; e < 8; ++e)
    vb8[e] = Xcol[(size_t)(kg * 8 + e) * HW];
  for (int s = 0; s < 8; ++s) {
    __syncthreads();   // prev iter's frag reads done
#pragma unroll
    for (int q = 0; q < 4; ++q) {
      ushort4 h4, l4;
      cvt4(ra[q], h4, l4);
      *(ushort4*)(Ab + lds_off(r0a, 0, kqa * 32 + q * 8)) = h4;
      *(ushort4*)(Ab + lds_off(r0a, 1, kqa * 32 + q * 8)) = l4;
    }
    {
      unsigned short bh[8], bl[8];
#pragma unroll
      for (int e = 0; e < 8; ++e) cvt2(vb8[e], bh[e], bl[e]);
      *(ushort4*)(Bb + lds_off(n_r, 0, kg * 16)) = make_ushort4(bh[0], bh[1], bh[2], bh[3]);
      *(ushort4*)(Bb + lds_off(n_r, 0, kg * 16 + 8)) = make_ushort4(bh[4], bh[5], bh[6], bh[7]);
      *(ushort4*)(Bb + lds_off(n_r, 1, kg * 16)) = make_ushort4(bl[0], bl[1], bl[2], bl[3]);
      *(ushort4*)(Bb + lds_off(n_r, 1, kg * 16 + 8)) = make_ushort4(bl[4], bl[5], bl[6], bl[7]);
    }
    __syncthreads();
    if (s < 7) {
      int k0 = (s + 1) * 32;
#pragma unroll
      for (int q = 0; q < 4; ++q)
        ra[q] = *(const float4*)(A + (size_t)r0a * 256 + k0 + kqa * 16 + q * 4);
#pragma unroll
      for (int e = 0; e < 8; ++e)
        vb8[e] = Xcol[(size_t)(k0 + kg * 8 + e) * HW];
    }
#pragma unroll
    for (int hb = 0; hb < 2; ++hb) {
      bf16x8 bh[4];
#pragma unroll
      for (int n = 0; n < 4; ++n)
        bh[n] = frag_ld(Bb, wc * 64 + n * 16 + (lane & 15), hb, lane);
#pragma unroll
      for (int m = 0; m < 4; ++m) {
        int arow = wr * 64 + m * 16 + (lane & 15);
        bf16x8 a0 = frag_ld(Ab, arow, 0, lane);
#pragma unroll
        for (int n = 0; n < 4; ++n)
          acc[m][n] = __builtin_amdgcn_mfma_f32_16x16x32_bf16(a0, bh[n], acc[m][n], 0, 0, 0);
        if (hb == 0) {
          bf16x8 a1 = frag_ld(Ab, arow, 1, lane);
#pragma unroll
          for (int n = 0; n < 4; ++n)
            acc[m][n] = __builtin_amdgcn_mfma_f32_16x16x32_bf16(a1, bh[n], acc[m][n], 0, 0, 0);
        }
      }
    }
  }
  float g = 0.f;
  if (MODE == 0) g = gsc[0];
#pragma unroll
  for (int m = 0; m < 4; ++m)
#pragma unroll
    for (int n = 0; n < 4; ++n) {
      int row = wr * 64 + m * 16 + ((lane >> 4) << 2);
      int col = nbase + wc * 64 + n * 16 + (lane & 15);
#pragma unroll
      for (int r2 = 0; r2 < 4; ++r2) {
        size_t o = (size_t)(row + r2) * HW + col;
        float v = acc[m][n][r2];
        if (MODE == 0) OUTb[o] = g * v + Xb[o];
        else           OUTb[o] = v + bvec[row + r2];
      }
    }
}

// ------------------------------------------------------------ PAM q/k GEMM
// Full-image 1x1 conv: rows 0..31 = Wq, 32..63 = Wk; N = 6400, K = 256.
// Outputs: qt[b][n][32] (n-major, +bq), kf[b][32][n] (+bk). split-bf16.
__global__ __launch_bounds__(256) void qk_k(const float* __restrict__ X,
                                            const float* __restrict__ Wq,
                                            const float* __restrict__ bq,
                                            const float* __restrict__ Wk,
                                            const float* __restrict__ bk,
                                            float* __restrict__ qt,
                                            float* __restrict__ kf) {
  const int nbase = blockIdx.x * 256;
  const int b = blockIdx.y;
  const float* Xb = X + (size_t)b * CH * HW;
  __shared__ unsigned short lds[(64 + 256) * 64];  // A 8KB + B 32KB
  char* Ab = (char*)lds;
  char* Bb = (char*)lds + 8192;
  const int tid = threadIdx.x, lane = tid & 63, w = tid >> 6;
  const int ar = tid >> 2, akq = tid & 3;          // A staging
  const int n4 = (tid & 63) * 4, c0l = tid >> 6;   // B staging (256 rows)
  const float* Arow = (ar < 32) ? (Wq + (size_t)ar * CH) : (Wk + (size_t)(ar - 32) * CH);
  f32x4 acc[4][4] = {};
  float4 va[2], vb[8];
#pragma unroll
  for (int q = 0; q < 2; ++q)
    va[q] = *(const float4*)(Arow + akq * 8 + q * 4);
#pragma unroll
  for (int q = 0; q < 8; ++q)
    vb[q] = *(const float4*)(Xb + (size_t)(c0l + 4 * q) * HW + nbase + n4);
  for (int s = 0; s < 8; ++s) {
    __syncthreads();   // prev iter's frag reads done
#pragma unroll
    for (int q = 0; q < 2; ++q) {
      ushort4 h4, l4;
      cvt4(va[q], h4, l4);
      *(ushort4*)(Ab + lds_off(ar, 0, akq * 16 + q * 8)) = h4;
      *(ushort4*)(Ab + lds_off(ar, 1, akq * 16 + q * 8)) = l4;
    }
#pragma unroll
    for (int q = 0; q < 8; ++q) {
      int cc = c0l + 4 * q;
      float4 v = vb[q];
#pragma unroll
      for (int jj = 0; jj < 4; ++jj) {
        int j = (jj + tid) & 3;
        float e = (j == 0) ? v.x : (j == 1) ? v.y : (j == 2) ? v.z : v.w;
        unsigned short h, l;
        cvt2(e, h, l);
        int row = n4 + j;
        *(unsigned short*)(Bb + lds_off(row, 0, cc * 2)) = h;
        *(unsigned short*)(Bb + lds_off(row, 1, cc * 2)) = l;
      }
    }
    __syncthreads();
    float4 na[2], nb[8];
    if (s < 7) {
      const int k0 = (s + 1) * 32;
#pragma unroll
      for (int q = 0; q < 2; ++q)
        na[q] = *(const float4*)(Arow + k0 + akq * 8 + q * 4);
#pragma unroll
      for (int q = 0; q < 8; ++q)
        nb[q] = *(const float4*)(Xb + (size_t)(k0 + c0l + 4 * q) * HW + nbase + n4);
    }
    bf16x8 bfr[2][4];
#pragma unroll
    for (int h = 0; h < 2; ++h)
#pragma unroll
      for (int n = 0; n < 4; ++n)
        bfr[h][n] = frag_ld(Bb, w * 64 + n * 16 + (lane & 15), h, lane);
#pragma unroll
    for (int m = 0; m < 4; ++m) {
      int arow2 = m * 16 + (lane & 15);
      bf16x8 a0 = frag_ld(Ab, arow2, 0, lane);
      bf16x8 a1 = frag_ld(Ab, arow2, 1, lane);
#pragma unroll
      for (int n = 0; n < 4; ++n)
        acc[m][n] = __builtin_amdgcn_mfma_f32_16x16x32_bf16(a0, bfr[0][n], acc[m][n], 0, 0, 0);
#pragma unroll
      for (int n = 0; n < 4; ++n)
        acc[m][n] = __builtin_amdgcn_mfma_f32_16x16x32_bf16(a0, bfr[1][n], acc[m][n], 0, 0, 0);
#pragma unroll
      for (int n = 0; n < 4; ++n)
        acc[m][n] = __builtin_amdgcn_mfma_f32_16x16x32_bf16(a1, bfr[0][n], acc[m][n], 0, 0, 0);
    }
#pragma unroll
    for (int q = 0; q < 2; ++q) va[q] = na[q];
#pragma unroll
    for (int q = 0; q < 8; ++q) vb[q] = nb[q];
  }
#pragma unroll
  for (int m = 0; m < 4; ++m)
#pragma unroll
    for (int n = 0; n < 4; ++n) {
      int row = m * 16 + ((lane >> 4) << 2);
      int col = nbase + w * 64 + n * 16 + (lane & 15);
#pragma unroll
      for (int r2 = 0; r2 < 4; ++r2) {
        int rr = row + r2;
        float v = acc[m][n][r2];
        if (rr < 32) qt[((size_t)b * HW + col) * 32 + rr] = v + bq[rr];
        else         kf[((size_t)b * 32 + (rr - 32)) * HW + col] = v + bk[rr - 32];
      }
    }
}

// --------------------------------------------------- PAM energy + softmax
__global__ __launch_bounds__(256) void pam_es_k(const float* __restrict__ qt,
                                                const float* __restrict__ kf,
                                                float* __restrict__ Pbuf) {
  const int ccb = blockIdx.x;
  const int ck = ccb >> 4, b = ccb & 15;
  const int gi = ck / 5, gj = ck % 5;
  const int pbase = gi * 16 * IMW + gj * 16;
  float* Pc = Pbuf + (size_t)ccb * 65536;
  __shared__ float qs[256][32];
  __shared__ float S[32][256];
  const int tid = threadIdx.x;
  const float* qb = qt + (size_t)b * HW * 32;
#pragma unroll
  for (int qq = 0; qq < 8; ++qq) {
    int j = (tid >> 3) + 32 * qq;
    int nj = pbase + (j >> 4) * IMW + (j & 15);
    float4 v = *(const float4*)(qb + (size_t)nj * 32 + (tid & 7) * 4);
    *(float4*)&qs[j][(tid & 7) * 4] = v;
  }
  const int nt = pbase + (tid >> 4) * IMW + (tid & 15);
  const float* kb = kf + (size_t)b * 32 * HW;
  float kc[32];
#pragma unroll
  for (int kk = 0; kk < 32; ++kk) kc[kk] = kb[(size_t)kk * HW + nt];
  __syncthreads();
  const int w = tid >> 6, lane = tid & 63;
  for (int p = 0; p < 8; ++p) {
#pragma unroll 4
    for (int j2 = 0; j2 < 32; ++j2) {
      int row = p * 32 + j2;
      float s = 0.f;
#pragma unroll
      for (int k8 = 0; k8 < 8; ++k8) {
        float4 qv = *(const float4*)&qs[row][k8 * 4];
        s = fmaf(qv.x, kc[k8 * 4 + 0], s);
        s = fmaf(qv.y, kc[k8 * 4 + 1], s);
        s = fmaf(qv.z, kc[k8 * 4 + 2], s);
        s = fmaf(qv.w, kc[k8 * 4 + 3], s);
      }
      S[j2][tid] = s;
    }
    __syncthreads();
#pragma unroll
    for (int rr = 0; rr < 8; ++rr) {
      int jj = w * 8 + rr;
      float4 v = *(const float4*)&S[jj][lane << 2];
      float m = fmaxf(fmaxf(v.x, v.y), fmaxf(v.z, v.w));
      for (int o = 32; o; o >>= 1) m = fmaxf(m, __shfl_xor(m, o));
      float4 pv;
      pv.x = __expf(v.x - m); pv.y = __expf(v.y - m);
      pv.z = __expf(v.z - m); pv.w = __expf(v.w - m);
      float s = (pv.x + pv.y) + (pv.z + pv.w);
      for (int o = 32; o; o >>= 1) s += __shfl_xor(s, o);
      const float inv = 1.f / s;
      pv.x *= inv; pv.y *= inv; pv.z *= inv; pv.w *= inv;
      *(float4*)&Pc[(size_t)(p * 32 + jj) * 256 + (lane << 2)] = pv;
    }
    __syncthreads();
  }
}

// ---------------------------------------------------------------- PAM PV
// R15 j-split: grid (2, 400). Block (jh, ccb) computes out[d][j] for
// j in [jh*128, jh*128+128): reads ONLY P rows in that range (B-operand)
// and writes the result into those same rows as a flat [256][128] region
// (Oc[d*128 + jloc]). Fixed bijection per ccb -> gram invariant.
// 512 thr, 8 waves 4x2 of 64x64 (acc[4][4]); 48KB LDS; 2 blocks/CU.
__global__ __launch_bounds__(512, 4) void pam_pv_k(float* __restrict__ P,
                                                   const float* __restrict__ V,
                                                   const float* __restrict__ fS,
                                                   const float* __restrict__ fT,
                                                   const float* __restrict__ gsc, int t) {
  const int jh = blockIdx.x;
  const int ccb = blockIdx.y;
  const int ck = ccb >> 4, b = ccb & 15;
  const int gi = ck / 5, gj = ck % 5;
  const float* Xb = (t ? fT : fS) + (size_t)b * CH * HW;
  const float* Vb = V + (size_t)b * CH * HW;
  float* Pc = P + (size_t)ccb * 65536;
  const float* Pr = Pc + (size_t)jh * 32768;   // this block's P rows [128][256]
  float* Oc = Pc + (size_t)jh * 32768;         // out region, flat [256][128]
  __shared__ unsigned short lds[(256 + 128) * 64];  // A(V) 32KB + B(P) 16KB
  char* Ab = (char*)lds;
  char* Bb = (char*)lds + 32768;
  const int tid = threadIdx.x, lane = tid & 63, w = tid >> 6;
  const int wr = w >> 1, wc = w & 1;           // 4x2 waves -> 64x64 each
  const int r0a = tid >> 1, kqa = tid & 1;     // A: rows 0-255, 16 k each
  const int r0b = tid >> 2, kqb = tid & 3;     // B: rows 0-127, 8 k each
  const int pbase = gi * 16 * IMW + gj * 16;
  f32x4 acc[4][4] = {};
  float4 va[4], vp[2];
  {
    int jj = kqa * 16;
    int ngl = pbase + (jj >> 4) * IMW;         // jj is 16-aligned
#pragma unroll
    for (int q = 0; q < 4; ++q)
      va[q] = *(const float4*)(Vb + (size_t)r0a * HW + ngl + q * 4);
#pragma unroll
    for (int q = 0; q < 2; ++q)
      vp[q] = *(const float4*)(Pr + (size_t)r0b * 256 + kqb * 8 + q * 4);
  }
  for (int s = 0; s < 8; ++s) {
    __syncthreads();   // prev iter's frag reads done
#pragma unroll
    for (int q = 0; q < 4; ++q) {
      ushort4 h4, l4;
      cvt4(va[q], h4, l4);
      *(ushort4*)(Ab + lds_off(r0a, 0, kqa * 32 + q * 8)) = h4;
      *(ushort4*)(Ab + lds_off(r0a, 1, kqa * 32 + q * 8)) = l4;
    }
#pragma unroll
    for (int q = 0; q < 2; ++q) {
      ushort4 h4, l4;
      cvt4(vp[q], h4, l4);
      *(ushort4*)(Bb + lds_off(r0b, 0, kqb * 16 + q * 8)) = h4;
      *(ushort4*)(Bb + lds_off(r0b, 1, kqb * 16 + q * 8)) = l4;
    }
    __syncthreads();
    if (s < 7) {
      int k0 = (s + 1) * 32;
      int jj = k0 + kqa * 16;
      int ngl = pbase + (jj >> 4) * IMW;
#pragma unroll
      for (int q = 0; q < 4; ++q)
        va[q] = *(const float4*)(Vb + (size_t)r0a * HW + ngl + q * 4);
#pragma unroll
      for (int q = 0; q < 2; ++q)
        vp[q] = *(const float4*)(Pr + (size_t)r0b * 256 + k0 + kqb * 8 + q * 4);
    }
#pragma unroll
    for (int hb = 0; hb < 2; ++hb) {
      bf16x8 bh[4];
#pragma unroll
      for (int n = 0; n < 4; ++n)
        bh[n] = frag_ld(Bb, wc * 64 + n * 16 + (lane & 15), hb, lane);
#pragma unroll
      for (int m = 0; m < 4; ++m) {
        int arow = wr * 64 + m * 16 + (lane & 15);
        bf16x8 a0 = frag_ld(Ab, arow, 0, lane);
#pragma unroll
        for (int n = 0; n < 4; ++n)
          acc[m][n] = __builtin_amdgcn_mfma_f32_16x16x32_bf16(a0, bh[n], acc[m][n], 0, 0, 0);
        if (hb == 0) {
          bf16x8 a1 = frag_ld(Ab, arow, 1, lane);
#pragma unroll
          for (int n = 0; n < 4; ++n)
            acc[m][n] = __builtin_amdgcn_mfma_f32_16x16x32_bf16(a1, bh[n], acc[m][n], 0, 0, 0);
        }
      }
    }
  }
  const float g = gsc[0];
#pragma unroll
  for (int m = 0; m < 4; ++m)
#pragma unroll
    for (int n = 0; n < 4; ++n) {
      int row = wr * 64 + m * 16 + ((lane >> 4) << 2);
      int jloc = wc * 64 + n * 16 + (lane & 15);
      int jg = jh * 128 + jloc;
      int ngl = pbase + (jg >> 4) * IMW + (jg & 15);
#pragma unroll
      for (int r2 = 0; r2 < 4; ++r2) {
        float v = g * acc[m][n][r2] + Xb[(size_t)(row + r2) * HW + ngl];
        Oc[(size_t)(row + r2) * 128 + jloc] = v;
      }
    }
}

// ------------------------------------------------------------- gram (MFMA)
__global__ __launch_bounds__(256) void gram_mfma_k(const float* __restrict__ Z,
                                                   size_t gStride, size_t bStride,
                                                   double* __restrict__ G) {
  const int tid = threadIdx.x, lane = tid & 63, w = tid >> 6;
  const float* Zg = Z + (size_t)blockIdx.y * gStride;
  const float* p = Zg + (size_t)(lane & 15) * bStride +
                   (size_t)blockIdx.x * 4096 + w * 1024 + ((lane >> 4) << 3);
  f32x4 acc = {};
#pragma unroll 4
  for (int s = 0; s < 32; ++s) {
    float4 v0 = *(const float4*)(p + s * 32);
    float4 v1 = *(const float4*)(p + s * 32 + 4);
    bf16x8 hi, lo;
    cvt8(v0, v1, hi, lo);
    acc = __builtin_amdgcn_mfma_f32_16x16x32_bf16(hi, hi, acc, 0, 0, 0);
    acc = __builtin_amdgcn_mfma_f32_16x16x32_bf16(hi, lo, acc, 0, 0, 0);
    acc = __builtin_amdgcn_mfma_f32_16x16x32_bf16(lo, hi, acc, 0, 0, 0);
  }
  double* Gt = G + (size_t)blockIdx.y * 256;
  const int col = lane & 15, row0 = (lane >> 4) << 2;
#pragma unroll
  for (int i = 0; i < 4; ++i)
    atomicAdd(&Gt[(size_t)(row0 + i) * 16 + col], (double)acc[i]);
}

// -------------------------------------------------------------- CKA pairs
__global__ __launch_bounds__(256) void cka_pair_k(const double* __restrict__ G,
                                                  double* __restrict__ losses) {
  const int q = blockIdx.x;
  const double* KX = (q == 0) ? G : G + 512 + (size_t)(q - 1) * 256;
  const double* KY = (q == 0) ? G + 256 : G + 512 + 6400 + (size_t)(q - 1) * 256;
  __shared__ double red[256];
  __shared__ double srm[16], scm[16];
  __shared__ double stm;
  const int tid = threadIdx.x;
  const int r = tid >> 4, c = tid & 15;

  auto center = [&](double k) -> double {
    red[tid] = k;
    __syncthreads();
    for (int off = 8; off; off >>= 1) {
      if (c < off) red[tid] += red[tid + off];
      __syncthreads();
    }
    if (c == 0) srm[r] = red[tid] * (1.0 / 16.0);
    __syncthreads();
    red[c * 16 + r] = k;
    __syncthreads();
    for (int off = 8; off; off >>= 1) {
      if (r < off) red[c * 16 + r] += red[c * 16 + r + off];
      __syncthreads();
    }
    if (r == 0) scm[c] = red[c * 16] * (1.0 / 16.0);
    __syncthreads();
    if (tid == 0) {
      double s = 0.0;
      for (int i = 0; i < 16; ++i) s += srm[i];
      stm = s * (1.0 / 16.0);
    }
    __syncthreads();
    double v = k - srm[r] - scm[c] + stm;
    __syncthreads();
    return v;
  };
  auto reduce_sum = [&](double v) -> double {
    red[tid] = v;
    __syncthreads();
    for (int off = 128; off; off >>= 1) {
      if (tid < off) red[tid] += red[tid + off];
      __syncthreads();
    }
    double s = red[0];
    __syncthreads();
    return s;
  };
  double cx = center(KX[tid]);
  double cy = center(KY[tid]);
  double h = reduce_sum(cx * cy);
  double v1 = reduce_sum(cx * cx);
  double v2 = reduce_sum(cy * cy);
  if (tid == 0) losses[q] = -log(fabs(h / (sqrt(v1) * sqrt(v2))) + 1e-8);
}

__global__ void cka_combine_k(const double* __restrict__ losses,
                              float* __restrict__ out) {
  if (threadIdx.x == 0) {
    out[0] = (float)losses[0];
    double s = 0.0;
    for (int q = 1; q <= 25; ++q) s += losses[q];
    out[1] = (float)(s * (1.0 / 25.0));
  }
}

extern "C" void kernel_launch(void* const* d_in, const int* in_sizes, int n_in,
                              void* d_out, int out_size, void* d_ws, size_t ws_size,
                              hipStream_t stream) {
  (void)in_sizes; (void)n_in; (void)out_size; (void)ws_size;
  const float* fS = (const float*)d_in[0];
  const float* fT = (const float*)d_in[1];
  const float* Wq = (const float*)d_in[2];
  const float* bq = (const float*)d_in[3];
  const float* Wk = (const float*)d_in[4];
  const float* bk = (const float*)d_in[5];
  const float* Wv = (const float*)d_in[6];
  const float* bv = (const float*)d_in[7];
  const float* gcam = (const float*)d_in[8];
  const float* gpam = (const float*)d_in[9];
  float* out = (float*)d_out;

  float* buf0 = (float*)d_ws;              // 26214400 floats
  float* buf1 = buf0 + 26214400;           // 26214400 floats
  double* G = (double*)(buf1 + 26214400);  // 13312 doubles
  float* Pbuf = buf1;                      // 400*65536
  float* qt = buf0;                        // 16*6400*32
  float* kf = buf0 + 3276800;              // 16*32*6400
  double* losses = (double*)buf0;          // 26 doubles, dead region at CKA time

  hipMemsetAsync(G, 0, 13312 * sizeof(double), stream);

  // ---- CAM ----
  cam_energy_k<<<dim3(8, 16, 2), 1024, 0, stream>>>(fS, fT, buf1);
  cam_softmax_k<<<dim3(256, 16, 2), 64, 0, stream>>>(buf1);
  for (int t = 0; t < 2; ++t) {
    ax_k<0><<<dim3(50, 16), 512, 0, stream>>>(buf1 + (size_t)t * BB * 65536, 65536,
                                              t ? fT : fS, buf0, nullptr, gcam);
    gram_mfma_k<<<dim3(400, 1), 256, 0, stream>>>(buf0, (size_t)0, (size_t)1638400,
                                                  G + t * 256);
  }
  // ---- PAM ----
  for (int t = 0; t < 2; ++t) {
    const float* X = t ? fT : fS;
    qk_k<<<dim3(25, 16), 256, 0, stream>>>(X, Wq, bq, Wk, bk, qt, kf);
    pam_es_k<<<dim3(400), 256, 0, stream>>>(qt, kf, Pbuf);
    ax_k<1><<<dim3(50, 16), 512, 0, stream>>>(Wv, 0, X, buf0, bv, nullptr);
    pam_pv_k<<<dim3(2, 400), 512, 0, stream>>>(Pbuf, buf0, fS, fT, gpam, t);
    gram_mfma_k<<<dim3(16, 25), 256, 0, stream>>>(Pbuf, (size_t)1048576, (size_t)65536,
                                                  G + 512 + t * 6400);
  }
  cka_pair_k<<<dim3(26), 256, 0, stream>>>(G, losses);
  cka_combine_k<<<dim3(1), 64, 0, stream>>>(losses, out);
}

// Round 16
// 992.654 us; speedup vs baseline: 1.0785x; 1.0785x over previous
//
#include <hip/hip_runtime.h>

// CriterionSA: CAM + grid-PAM + CKA loss.
// GEMMs in split-bf16 MFMA (hi/lo, 3 MFMAs: hh+hl+lh); cam_energy plain bf16
// (softmax saturated). Grams via MFMA split-bf16; fp32 acc -> fp64 atomics.
// CKA fp64, 26 parallel blocks.
// R16 = exact revert to R14 (best verified, 993us). R15's pam_pv j-split
// (+50% V traffic) and the co-compilation-induced cam regression are undone.
// ws layout (floats): buf0[26214400] | buf1[26214400] | G[13312 doubles]
// required ws = 209,821,696 bytes (~200.1 MiB) -- same as rounds 1-15.

typedef short bf16x8 __attribute__((ext_vector_type(8)));
typedef float f32x4 __attribute__((ext_vector_type(4)));

constexpr int BB = 16;    // batch
constexpr int CH = 256;   // channels
constexpr int HW = 6400;  // 80*80
constexpr int IMW = 80;

__device__ __forceinline__ int lds_off(int row, int half, int k2) {
  return row * 128 + ((((half << 6)) | k2) ^ ((row & 7) << 4));
}

__device__ __forceinline__ bf16x8 frag_ld(const char* base, int row, int half, int lane) {
  int off = row * 128 + ((((half << 6)) | ((lane >> 4) << 4)) ^ ((lane & 7) << 4));
  return *(const bf16x8*)(base + off);
}

__device__ __forceinline__ void cvt2(float x, unsigned short& h, unsigned short& l) {
  unsigned u = __float_as_uint(x);
  h = (unsigned short)(u >> 16);                       // truncated hi
  float r = x - __uint_as_float(u & 0xffff0000u);
  l = (unsigned short)(__float_as_uint(r) >> 16);      // truncated residual
}

__device__ __forceinline__ void cvt4(float4 v, ushort4& h, ushort4& l) {
  cvt2(v.x, h.x, l.x); cvt2(v.y, h.y, l.y);
  cvt2(v.z, h.z, l.z); cvt2(v.w, h.w, l.w);
}

__device__ __forceinline__ void cvt8(float4 v0, float4 v1, bf16x8& hi, bf16x8& lo) {
  unsigned short h, l;
  cvt2(v0.x, h, l); hi[0] = (short)h; lo[0] = (short)l;
  cvt2(v0.y, h, l); hi[1] = (short)h; lo[1] = (short)l;
  cvt2(v0.z, h, l); hi[2] = (short)h; lo[2] = (short)l;
  cvt2(v0.w, h, l); hi[3] = (short)h; lo[3] = (short)l;
  cvt2(v1.x, h, l); hi[4] = (short)h; lo[4] = (short)l;
  cvt2(v1.y, h, l); hi[5] = (short)h; lo[5] = (short)l;
  cvt2(v1.z, h, l); hi[6] = (short)h; lo[6] = (short)l;
  cvt2(v1.w, h, l); hi[7] = (short)h; lo[7] = (short)l;
}

__device__ __forceinline__ unsigned short bf_rnd(float x) {
  unsigned u = __float_as_uint(x);
  return (unsigned short)((u + 0x8000u) >> 16);
}

// ---------------------------------------------------------------- CAM energy
// Partial E[kc][t][b] = X(:,kslice) X(:,kslice)^T, kc=0..7 (K=800 each,
// 12 x 64 + zero-padded 32 tail). Grid = 256 blocks, 1024 thr (16 waves of
// 64x64 -> acc[4][4]). One LDS panel is both MFMA operands. Double-buffered.
__global__ __launch_bounds__(1024) void cam_energy_k(const float* __restrict__ fS,
                                                     const float* __restrict__ fT,
                                                     float* __restrict__ part) {
  const int kc = blockIdx.x, b = blockIdx.y, t = blockIdx.z;
  const float* X = (t ? fT : fS) + (size_t)b * CH * HW;
  __shared__ unsigned short lds[2 * 256 * 64];  // 2 x 32 KB panels
  const int tid = threadIdx.x, lane = tid & 63, w = tid >> 6;
  const int wr = w >> 2, wc = w & 3;            // 4x4 waves -> 64x64 each
  const int r0 = tid >> 2, kq = tid & 3;        // staging: 4 float4/thread
  const int half = kq >> 1, k2b = (kq & 1) * 32;
  const float* Xr = X + (size_t)r0 * HW + kc * 800 + kq * 16;
  f32x4 acc[4][4] = {};
  float4 v[4];
#pragma unroll
  for (int q = 0; q < 4; ++q) v[q] = *(const float4*)(Xr + q * 4);
  for (int it = 0; it < 13; ++it) {
    char* pb = (char*)lds + (it & 1) * 32768;
#pragma unroll
    for (int q = 0; q < 4; ++q) {
      ushort4 u;
      u.x = bf_rnd(v[q].x); u.y = bf_rnd(v[q].y);
      u.z = bf_rnd(v[q].z); u.w = bf_rnd(v[q].w);
      *(ushort4*)(pb + lds_off(r0, half, k2b + q * 8)) = u;
    }
    __syncthreads();
    float4 nv[4];
    if (it < 12) {
      const int nk = (it + 1) * 64;
      if (nk + kq * 16 < 800) {
        const float* Xn = Xr + nk;
#pragma unroll
        for (int q = 0; q < 4; ++q) nv[q] = *(const float4*)(Xn + q * 4);
      } else {
#pragma unroll
        for (int q = 0; q < 4; ++q) nv[q] = make_float4(0.f, 0.f, 0.f, 0.f);
      }
    }
#pragma unroll
    for (int h = 0; h < 2; ++h) {
      bf16x8 bh[4];
#pragma unroll
      for (int n = 0; n < 4; ++n)
        bh[n] = frag_ld(pb, wc * 64 + n * 16 + (lane & 15), h, lane);
#pragma unroll
      for (int m = 0; m < 4; ++m) {
        bf16x8 a = frag_ld(pb, wr * 64 + m * 16 + (lane & 15), h, lane);
#pragma unroll
        for (int n = 0; n < 4; ++n)
          acc[m][n] = __builtin_amdgcn_mfma_f32_16x16x32_bf16(a, bh[n], acc[m][n], 0, 0, 0);
      }
    }
#pragma unroll
    for (int q = 0; q < 4; ++q) v[q] = nv[q];
  }
  float* Eb = part + (((size_t)kc * 2 + t) * BB + b) * 65536;
#pragma unroll
  for (int m = 0; m < 4; ++m)
#pragma unroll
    for (int n = 0; n < 4; ++n) {
      int row = wr * 64 + m * 16 + ((lane >> 4) << 2);
      int col = wc * 64 + n * 16 + (lane & 15);
#pragma unroll
      for (int r2 = 0; r2 < 4; ++r2)
        Eb[(size_t)(row + r2) * 256 + col] = acc[m][n][r2];
    }
}

// ------------------------------------------------------------- CAM softmax
// attn = exp(rowmin - sum_p partE[p]) / rowsum, written into partial 0.
__global__ __launch_bounds__(64) void cam_softmax_k(float* __restrict__ part) {
  const int c = blockIdx.x, b = blockIdx.y, t = blockIdx.z;
  const size_t base = (((size_t)t * BB + b) * CH + c) * CH;
  const int lane = threadIdx.x;
  float4 x = make_float4(0.f, 0.f, 0.f, 0.f);
#pragma unroll
  for (int p = 0; p < 8; ++p) {
    float4 y = ((const float4*)(part + (size_t)p * 2097152 + base))[lane];
    x.x += y.x; x.y += y.y; x.z += y.z; x.w += y.w;
  }
  float mn = fminf(fminf(x.x, x.y), fminf(x.z, x.w));
  for (int o = 32; o; o >>= 1) mn = fminf(mn, __shfl_xor(mn, o));
  float4 p4;
  p4.x = __expf(mn - x.x); p4.y = __expf(mn - x.y);
  p4.z = __expf(mn - x.z); p4.w = __expf(mn - x.w);
  float s = (p4.x + p4.y) + (p4.z + p4.w);
  for (int o = 32; o; o >>= 1) s += __shfl_xor(s, o);
  const float inv = 1.0f / s;
  p4.x *= inv; p4.y *= inv; p4.z *= inv; p4.w *= inv;
  ((float4*)(part + base))[lane] = p4;
}

// ----------------------------------------------------- A(256x256) @ X GEMM
// MODE 0 (cam_out): OUT[c][n] = g*sum_d A[c][d] X[d][n] + X[c][n]
// MODE 1 (pam_V):   OUT[d][n] = sum_c Wv[d][c] X[c][n] + bv[d]
// 1024 thr, 16 waves (4x4 of 64x32 -> acc[4][2]); tile M=256 x N=128;
// double-buffered LDS (96KB, 1 barrier/step). X read once.
template <int MODE>
__global__ __launch_bounds__(1024) void ax_k(const float* __restrict__ Abase, int Astride,
                                             const float* __restrict__ X,
                                             float* __restrict__ OUT,
                                             const float* __restrict__ bvec,
                                             const float* __restrict__ gsc) {
  const int nt = blockIdx.x;
  const int b = blockIdx.y;
  const float* A = Abase + (size_t)b * Astride;
  const float* Xb = X + (size_t)b * CH * HW;
  float* OUTb = OUT + (size_t)b * CH * HW;
  const int nbase = nt * 128;
  __shared__ unsigned short lds[2 * (256 + 128) * 64];  // dbuf x (A 32KB + B 16KB)
  const int tid = threadIdx.x, lane = tid & 63, w = tid >> 6;
  const int wr = w >> 2, wc = w & 3;             // 4x4 waves -> 64x32 each
  const int r0 = tid >> 2, kq = tid & 3;         // A staging: 2 float4/thread
  const int n_r = tid & 127, kg = tid >> 7;      // B staging: row + 4-k group
  const float* Xcol = Xb + nbase + n_r;
  f32x4 acc[4][2] = {};
  float4 ra[2];
  float vb4[4];
#pragma unroll
  for (int q = 0; q < 2; ++q)
    ra[q] = *(const float4*)(A + (size_t)r0 * 256 + kq * 8 + q * 4);
#pragma unroll
  for (int e = 0; e < 4; ++e)
    vb4[e] = Xcol[(size_t)(kg * 4 + e) * HW];
  for (int s = 0; s < 8; ++s) {
    char* Ab = (char*)lds + (s & 1) * 49152;
    char* Bb = Ab + 32768;
#pragma unroll
    for (int q = 0; q < 2; ++q) {
      ushort4 h4, l4;
      cvt4(ra[q], h4, l4);
      *(ushort4*)(Ab + lds_off(r0, 0, kq * 16 + q * 8)) = h4;
      *(ushort4*)(Ab + lds_off(r0, 1, kq * 16 + q * 8)) = l4;
    }
    {
      unsigned short bh[4], bl[4];
#pragma unroll
      for (int e = 0; e < 4; ++e) cvt2(vb4[e], bh[e], bl[e]);
      *(ushort4*)(Bb + lds_off(n_r, 0, kg * 8)) = make_ushort4(bh[0], bh[1], bh[2], bh[3]);
      *(ushort4*)(Bb + lds_off(n_r, 1, kg * 8)) = make_ushort4(bl[0], bl[1], bl[2], bl[3]);
    }
    __syncthreads();
    if (s < 7) {
      int k0 = (s + 1) * 32;
#pragma unroll
      for (int q = 0; q < 2; ++q)
        ra[q] = *(const float4*)(A + (size_t)r0 * 256 + k0 + kq * 8 + q * 4);
#pragma unroll
      for (int e = 0; e < 4; ++e)
        vb4[e] = Xcol[(size_t)(k0 + kg * 4 + e) * HW];
    }
    bf16x8 bfr[2][2];
#pragma unroll
    for (int h = 0; h < 2; ++h)
#pragma unroll
      for (int n = 0; n < 2; ++n)
        bfr[h][n] = frag_ld(Bb, wc * 32 + n * 16 + (lane & 15), h, lane);
#pragma unroll
    for (int m = 0; m < 4; ++m) {
      int arow = wr * 64 + m * 16 + (lane & 15);
      bf16x8 a0 = frag_ld(Ab, arow, 0, lane);
      bf16x8 a1 = frag_ld(Ab, arow, 1, lane);
#pragma unroll
      for (int n = 0; n < 2; ++n)
        acc[m][n] = __builtin_amdgcn_mfma_f32_16x16x32_bf16(a0, bfr[0][n], acc[m][n], 0, 0, 0);
#pragma unroll
      for (int n = 0; n < 2; ++n)
        acc[m][n] = __builtin_amdgcn_mfma_f32_16x16x32_bf16(a0, bfr[1][n], acc[m][n], 0, 0, 0);
#pragma unroll
      for (int n = 0; n < 2; ++n)
        acc[m][n] = __builtin_amdgcn_mfma_f32_16x16x32_bf16(a1, bfr[0][n], acc[m][n], 0, 0, 0);
    }
  }
  float g = 0.f;
  if (MODE == 0) g = gsc[0];
#pragma unroll
  for (int m = 0; m < 4; ++m)
#pragma unroll
    for (int n = 0; n < 2; ++n) {
      int row = wr * 64 + m * 16 + ((lane >> 4) << 2);
      int col = nbase + wc * 32 + n * 16 + (lane & 15);
#pragma unroll
      for (int r2 = 0; r2 < 4; ++r2) {
        size_t o = (size_t)(row + r2) * HW + col;
        float v = acc[m][n][r2];
        if (MODE == 0) OUTb[o] = g * v + Xb[o];
        else           OUTb[o] = v + bvec[row + r2];
      }
    }
}

// ------------------------------------------------------------ PAM q/k GEMM
// Full-image 1x1 conv: rows 0..31 = Wq, 32..63 = Wk; N = 6400, K = 256.
// Outputs: qt[b][n][32] (n-major, +bq), kf[b][32][n] (+bk). split-bf16.
__global__ __launch_bounds__(256) void qk_k(const float* __restrict__ X,
                                            const float* __restrict__ Wq,
                                            const float* __restrict__ bq,
                                            const float* __restrict__ Wk,
                                            const float* __restrict__ bk,
                                            float* __restrict__ qt,
                                            float* __restrict__ kf) {
  const int nbase = blockIdx.x * 256;
  const int b = blockIdx.y;
  const float* Xb = X + (size_t)b * CH * HW;
  __shared__ unsigned short lds[(64 + 256) * 64];  // A 8KB + B 32KB
  char* Ab = (char*)lds;
  char* Bb = (char*)lds + 8192;
  const int tid = threadIdx.x, lane = tid & 63, w = tid >> 6;
  const int ar = tid >> 2, akq = tid & 3;          // A staging
  const int n4 = (tid & 63) * 4, c0l = tid >> 6;   // B staging (256 rows)
  const float* Arow = (ar < 32) ? (Wq + (size_t)ar * CH) : (Wk + (size_t)(ar - 32) * CH);
  f32x4 acc[4][4] = {};
  float4 va[2], vb[8];
#pragma unroll
  for (int q = 0; q < 2; ++q)
    va[q] = *(const float4*)(Arow + akq * 8 + q * 4);
#pragma unroll
  for (int q = 0; q < 8; ++q)
    vb[q] = *(const float4*)(Xb + (size_t)(c0l + 4 * q) * HW + nbase + n4);
  for (int s = 0; s < 8; ++s) {
    __syncthreads();   // prev iter's frag reads done
#pragma unroll
    for (int q = 0; q < 2; ++q) {
      ushort4 h4, l4;
      cvt4(va[q], h4, l4);
      *(ushort4*)(Ab + lds_off(ar, 0, akq * 16 + q * 8)) = h4;
      *(ushort4*)(Ab + lds_off(ar, 1, akq * 16 + q * 8)) = l4;
    }
#pragma unroll
    for (int q = 0; q < 8; ++q) {
      int cc = c0l + 4 * q;
      float4 v = vb[q];
#pragma unroll
      for (int jj = 0; jj < 4; ++jj) {
        int j = (jj + tid) & 3;
        float e = (j == 0) ? v.x : (j == 1) ? v.y : (j == 2) ? v.z : v.w;
        unsigned short h, l;
        cvt2(e, h, l);
        int row = n4 + j;
        *(unsigned short*)(Bb + lds_off(row, 0, cc * 2)) = h;
        *(unsigned short*)(Bb + lds_off(row, 1, cc * 2)) = l;
      }
    }
    __syncthreads();
    float4 na[2], nb[8];
    if (s < 7) {
      const int k0 = (s + 1) * 32;
#pragma unroll
      for (int q = 0; q < 2; ++q)
        na[q] = *(const float4*)(Arow + k0 + akq * 8 + q * 4);
#pragma unroll
      for (int q = 0; q < 8; ++q)
        nb[q] = *(const float4*)(Xb + (size_t)(k0 + c0l + 4 * q) * HW + nbase + n4);
    }
    bf16x8 bfr[2][4];
#pragma unroll
    for (int h = 0; h < 2; ++h)
#pragma unroll
      for (int n = 0; n < 4; ++n)
        bfr[h][n] = frag_ld(Bb, w * 64 + n * 16 + (lane & 15), h, lane);
#pragma unroll
    for (int m = 0; m < 4; ++m) {
      int arow2 = m * 16 + (lane & 15);
      bf16x8 a0 = frag_ld(Ab, arow2, 0, lane);
      bf16x8 a1 = frag_ld(Ab, arow2, 1, lane);
#pragma unroll
      for (int n = 0; n < 4; ++n)
        acc[m][n] = __builtin_amdgcn_mfma_f32_16x16x32_bf16(a0, bfr[0][n], acc[m][n], 0, 0, 0);
#pragma unroll
      for (int n = 0; n < 4; ++n)
        acc[m][n] = __builtin_amdgcn_mfma_f32_16x16x32_bf16(a0, bfr[1][n], acc[m][n], 0, 0, 0);
#pragma unroll
      for (int n = 0; n < 4; ++n)
        acc[m][n] = __builtin_amdgcn_mfma_f32_16x16x32_bf16(a1, bfr[0][n], acc[m][n], 0, 0, 0);
    }
#pragma unroll
    for (int q = 0; q < 2; ++q) va[q] = na[q];
#pragma unroll
    for (int q = 0; q < 8; ++q) vb[q] = nb[q];
  }
#pragma unroll
  for (int m = 0; m < 4; ++m)
#pragma unroll
    for (int n = 0; n < 4; ++n) {
      int row = m * 16 + ((lane >> 4) << 2);
      int col = nbase + w * 64 + n * 16 + (lane & 15);
#pragma unroll
      for (int r2 = 0; r2 < 4; ++r2) {
        int rr = row + r2;
        float v = acc[m][n][r2];
        if (rr < 32) qt[((size_t)b * HW + col) * 32 + rr] = v + bq[rr];
        else         kf[((size_t)b * 32 + (rr - 32)) * HW + col] = v + bk[rr - 32];
      }
    }
}

// --------------------------------------------------- PAM energy + softmax
__global__ __launch_bounds__(256) void pam_es_k(const float* __restrict__ qt,
                                                const float* __restrict__ kf,
                                                float* __restrict__ Pbuf) {
  const int ccb = blockIdx.x;
  const int ck = ccb >> 4, b = ccb & 15;
  const int gi = ck / 5, gj = ck % 5;
  const int pbase = gi * 16 * IMW + gj * 16;
  float* Pc = Pbuf + (size_t)ccb * 65536;
  __shared__ float qs[256][32];
  __shared__ float S[32][256];
  const int tid = threadIdx.x;
  const float* qb = qt + (size_t)b * HW * 32;
#pragma unroll
  for (int qq = 0; qq < 8; ++qq) {
    int j = (tid >> 3) + 32 * qq;
    int nj = pbase + (j >> 4) * IMW + (j & 15);
    float4 v = *(const float4*)(qb + (size_t)nj * 32 + (tid & 7) * 4);
    *(float4*)&qs[j][(tid & 7) * 4] = v;
  }
  const int nt = pbase + (tid >> 4) * IMW + (tid & 15);
  const float* kb = kf + (size_t)b * 32 * HW;
  float kc[32];
#pragma unroll
  for (int kk = 0; kk < 32; ++kk) kc[kk] = kb[(size_t)kk * HW + nt];
  __syncthreads();
  const int w = tid >> 6, lane = tid & 63;
  for (int p = 0; p < 8; ++p) {
#pragma unroll 4
    for (int j2 = 0; j2 < 32; ++j2) {
      int row = p * 32 + j2;
      float s = 0.f;
#pragma unroll
      for (int k8 = 0; k8 < 8; ++k8) {
        float4 qv = *(const float4*)&qs[row][k8 * 4];
        s = fmaf(qv.x, kc[k8 * 4 + 0], s);
        s = fmaf(qv.y, kc[k8 * 4 + 1], s);
        s = fmaf(qv.z, kc[k8 * 4 + 2], s);
        s = fmaf(qv.w, kc[k8 * 4 + 3], s);
      }
      S[j2][tid] = s;
    }
    __syncthreads();
#pragma unroll
    for (int rr = 0; rr < 8; ++rr) {
      int jj = w * 8 + rr;
      float4 v = *(const float4*)&S[jj][lane << 2];
      float m = fmaxf(fmaxf(v.x, v.y), fmaxf(v.z, v.w));
      for (int o = 32; o; o >>= 1) m = fmaxf(m, __shfl_xor(m, o));
      float4 pv;
      pv.x = __expf(v.x - m); pv.y = __expf(v.y - m);
      pv.z = __expf(v.z - m); pv.w = __expf(v.w - m);
      float s = (pv.x + pv.y) + (pv.z + pv.w);
      for (int o = 32; o; o >>= 1) s += __shfl_xor(s, o);
      const float inv = 1.f / s;
      pv.x *= inv; pv.y *= inv; pv.z *= inv; pv.w *= inv;
      *(float4*)&Pc[(size_t)(p * 32 + jj) * 256 + (lane << 2)] = pv;
    }
    __syncthreads();
  }
}

// ---------------------------------------------------------------- PAM PV
// One 1024-thr block per ccb: out[d][j] = g*sum_n V[d][n] P[j][n] + X[d][n(j)],
// written over P[ccb] after all reads complete. 16 waves of 64x64 (acc[4][4]),
// h-outer MFMA (hh+lh with b_hi, hl with b_lo), dbuf LDS, reg prefetch.
__global__ __launch_bounds__(1024) void pam_pv_k(float* __restrict__ P,
                                                 const float* __restrict__ V,
                                                 const float* __restrict__ fS,
                                                 const float* __restrict__ fT,
                                                 const float* __restrict__ gsc, int t) {
  const int ccb = blockIdx.x;
  const int ck = ccb >> 4, b = ccb & 15;
  const int gi = ck / 5, gj = ck % 5;
  const float* Xb = (t ? fT : fS) + (size_t)b * CH * HW;
  const float* Vb = V + (size_t)b * CH * HW;
  float* Pc = P + (size_t)ccb * 65536;
  __shared__ unsigned short lds[2 * 2 * 256 * 64];  // dbuf x (A 32KB + B 32KB)
  const int tid = threadIdx.x, lane = tid & 63, w = tid >> 6;
  const int wr = w >> 2, wc = w & 3;       // 4x4 waves -> 64x64 each
  const int r0 = tid >> 2, kq = tid & 3;   // staging: row + k-octet (8 k)
  const int pbase = gi * 16 * IMW + gj * 16;
  f32x4 acc[4][4] = {};
  float4 va[2], vb[2];
  {
    int jj = kq * 8;
    int ngl = pbase + (jj >> 4) * IMW + (jj & 15);
    va[0] = *(const float4*)(Vb + (size_t)r0 * HW + ngl);
    va[1] = *(const float4*)(Vb + (size_t)r0 * HW + ngl + 4);
    vb[0] = *(const float4*)(Pc + (size_t)r0 * 256 + jj);
    vb[1] = *(const float4*)(Pc + (size_t)r0 * 256 + jj + 4);
  }
  for (int s = 0; s < 8; ++s) {
    char* Ab = (char*)lds + (s & 1) * 65536;
    char* Bb = Ab + 32768;
    {
      ushort4 h4, l4;
      cvt4(va[0], h4, l4);
      *(ushort4*)(Ab + lds_off(r0, 0, kq * 16)) = h4;
      *(ushort4*)(Ab + lds_off(r0, 1, kq * 16)) = l4;
      cvt4(va[1], h4, l4);
      *(ushort4*)(Ab + lds_off(r0, 0, kq * 16 + 8)) = h4;
      *(ushort4*)(Ab + lds_off(r0, 1, kq * 16 + 8)) = l4;
      cvt4(vb[0], h4, l4);
      *(ushort4*)(Bb + lds_off(r0, 0, kq * 16)) = h4;
      *(ushort4*)(Bb + lds_off(r0, 1, kq * 16)) = l4;
      cvt4(vb[1], h4, l4);
      *(ushort4*)(Bb + lds_off(r0, 0, kq * 16 + 8)) = h4;
      *(ushort4*)(Bb + lds_off(r0, 1, kq * 16 + 8)) = l4;
    }
    __syncthreads();
    if (s < 7) {
      int k0 = (s + 1) * 32;
      int jj = k0 + kq * 8;
      int ngl = pbase + (jj >> 4) * IMW + (jj & 15);
      va[0] = *(const float4*)(Vb + (size_t)r0 * HW + ngl);
      va[1] = *(const float4*)(Vb + (size_t)r0 * HW + ngl + 4);
      vb[0] = *(const float4*)(Pc + (size_t)r0 * 256 + k0 + kq * 8);
      vb[1] = *(const float4*)(Pc + (size_t)r0 * 256 + k0 + kq * 8 + 4);
    }
#pragma unroll
    for (int hb = 0; hb < 2; ++hb) {
      bf16x8 bh[4];
#pragma unroll
      for (int n = 0; n < 4; ++n)
        bh[n] = frag_ld(Bb, wc * 64 + n * 16 + (lane & 15), hb, lane);
#pragma unroll
      for (int m = 0; m < 4; ++m) {
        int arow = wr * 64 + m * 16 + (lane & 15);
        bf16x8 a0 = frag_ld(Ab, arow, 0, lane);
#pragma unroll
        for (int n = 0; n < 4; ++n)
          acc[m][n] = __builtin_amdgcn_mfma_f32_16x16x32_bf16(a0, bh[n], acc[m][n], 0, 0, 0);
        if (hb == 0) {
          bf16x8 a1 = frag_ld(Ab, arow, 1, lane);
#pragma unroll
          for (int n = 0; n < 4; ++n)
            acc[m][n] = __builtin_amdgcn_mfma_f32_16x16x32_bf16(a1, bh[n], acc[m][n], 0, 0, 0);
        }
      }
    }
  }
  const float g = gsc[0];
#pragma unroll
  for (int m = 0; m < 4; ++m)
#pragma unroll
    for (int n = 0; n < 4; ++n) {
      int row = wr * 64 + m * 16 + ((lane >> 4) << 2);
      int col = wc * 64 + n * 16 + (lane & 15);
      int ngl = pbase + (col >> 4) * IMW + (col & 15);
#pragma unroll
      for (int r2 = 0; r2 < 4; ++r2) {
        float v = g * acc[m][n][r2] + Xb[(size_t)(row + r2) * HW + ngl];
        Pc[(size_t)(row + r2) * 256 + col] = v;
      }
    }
}

// ------------------------------------------------------------- gram (MFMA)
__global__ __launch_bounds__(256) void gram_mfma_k(const float* __restrict__ Z,
                                                   size_t gStride, size_t bStride,
                                                   double* __restrict__ G) {
  const int tid = threadIdx.x, lane = tid & 63, w = tid >> 6;
  const float* Zg = Z + (size_t)blockIdx.y * gStride;
  const float* p = Zg + (size_t)(lane & 15) * bStride +
                   (size_t)blockIdx.x * 4096 + w * 1024 + ((lane >> 4) << 3);
  f32x4 acc = {};
#pragma unroll 4
  for (int s = 0; s < 32; ++s) {
    float4 v0 = *(const float4*)(p + s * 32);
    float4 v1 = *(const float4*)(p + s * 32 + 4);
    bf16x8 hi, lo;
    cvt8(v0, v1, hi, lo);
    acc = __builtin_amdgcn_mfma_f32_16x16x32_bf16(hi, hi, acc, 0, 0, 0);
    acc = __builtin_amdgcn_mfma_f32_16x16x32_bf16(hi, lo, acc, 0, 0, 0);
    acc = __builtin_amdgcn_mfma_f32_16x16x32_bf16(lo, hi, acc, 0, 0, 0);
  }
  double* Gt = G + (size_t)blockIdx.y * 256;
  const int col = lane & 15, row0 = (lane >> 4) << 2;
#pragma unroll
  for (int i = 0; i < 4; ++i)
    atomicAdd(&Gt[(size_t)(row0 + i) * 16 + col], (double)acc[i]);
}

// -------------------------------------------------------------- CKA pairs
__global__ __launch_bounds__(256) void cka_pair_k(const double* __restrict__ G,
                                                  double* __restrict__ losses) {
  const int q = blockIdx.x;
  const double* KX = (q == 0) ? G : G + 512 + (size_t)(q - 1) * 256;
  const double* KY = (q == 0) ? G + 256 : G + 512 + 6400 + (size_t)(q - 1) * 256;
  __shared__ double red[256];
  __shared__ double srm[16], scm[16];
  __shared__ double stm;
  const int tid = threadIdx.x;
  const int r = tid >> 4, c = tid & 15;

  auto center = [&](double k) -> double {
    red[tid] = k;
    __syncthreads();
    for (int off = 8; off; off >>= 1) {
      if (c < off) red[tid] += red[tid + off];
      __syncthreads();
    }
    if (c == 0) srm[r] = red[tid] * (1.0 / 16.0);
    __syncthreads();
    red[c * 16 + r] = k;
    __syncthreads();
    for (int off = 8; off; off >>= 1) {
      if (r < off) red[c * 16 + r] += red[c * 16 + r + off];
      __syncthreads();
    }
    if (r == 0) scm[c] = red[c * 16] * (1.0 / 16.0);
    __syncthreads();
    if (tid == 0) {
      double s = 0.0;
      for (int i = 0; i < 16; ++i) s += srm[i];
      stm = s * (1.0 / 16.0);
    }
    __syncthreads();
    double v = k - srm[r] - scm[c] + stm;
    __syncthreads();
    return v;
  };
  auto reduce_sum = [&](double v) -> double {
    red[tid] = v;
    __syncthreads();
    for (int off = 128; off; off >>= 1) {
      if (tid < off) red[tid] += red[tid + off];
      __syncthreads();
    }
    double s = red[0];
    __syncthreads();
    return s;
  };
  double cx = center(KX[tid]);
  double cy = center(KY[tid]);
  double h = reduce_sum(cx * cy);
  double v1 = reduce_sum(cx * cx);
  double v2 = reduce_sum(cy * cy);
  if (tid == 0) losses[q] = -log(fabs(h / (sqrt(v1) * sqrt(v2))) + 1e-8);
}

__global__ void cka_combine_k(const double* __restrict__ losses,
                              float* __restrict__ out) {
  if (threadIdx.x == 0) {
    out[0] = (float)losses[0];
    double s = 0.0;
    for (int q = 1; q <= 25; ++q) s += losses[q];
    out[1] = (float)(s * (1.0 / 25.0));
  }
}

extern "C" void kernel_launch(void* const* d_in, const int* in_sizes, int n_in,
                              void* d_out, int out_size, void* d_ws, size_t ws_size,
                              hipStream_t stream) {
  (void)in_sizes; (void)n_in; (void)out_size; (void)ws_size;
  const float* fS = (const float*)d_in[0];
  const float* fT = (const float*)d_in[1];
  const float* Wq = (const float*)d_in[2];
  const float* bq = (const float*)d_in[3];
  const float* Wk = (const float*)d_in[4];
  const float* bk = (const float*)d_in[5];
  const float* Wv = (const float*)d_in[6];
  const float* bv = (const float*)d_in[7];
  const float* gcam = (const float*)d_in[8];
  const float* gpam = (const float*)d_in[9];
  float* out = (float*)d_out;

  float* buf0 = (float*)d_ws;              // 26214400 floats
  float* buf1 = buf0 + 26214400;           // 26214400 floats
  double* G = (double*)(buf1 + 26214400);  // 13312 doubles
  float* Pbuf = buf1;                      // 400*65536
  float* qt = buf0;                        // 16*6400*32
  float* kf = buf0 + 3276800;              // 16*32*6400
  double* losses = (double*)buf0;          // 26 doubles, dead region at CKA time

  hipMemsetAsync(G, 0, 13312 * sizeof(double), stream);

  // ---- CAM ----
  cam_energy_k<<<dim3(8, 16, 2), 1024, 0, stream>>>(fS, fT, buf1);
  cam_softmax_k<<<dim3(256, 16, 2), 64, 0, stream>>>(buf1);
  for (int t = 0; t < 2; ++t) {
    ax_k<0><<<dim3(50, 16), 1024, 0, stream>>>(buf1 + (size_t)t * BB * 65536, 65536,
                                               t ? fT : fS, buf0, nullptr, gcam);
    gram_mfma_k<<<dim3(400, 1), 256, 0, stream>>>(buf0, (size_t)0, (size_t)1638400,
                                                  G + t * 256);
  }
  // ---- PAM ----
  for (int t = 0; t < 2; ++t) {
    const float* X = t ? fT : fS;
    qk_k<<<dim3(25, 16), 256, 0, stream>>>(X, Wq, bq, Wk, bk, qt, kf);
    pam_es_k<<<dim3(400), 256, 0, stream>>>(qt, kf, Pbuf);
    ax_k<1><<<dim3(50, 16), 1024, 0, stream>>>(Wv, 0, X, buf0, bv, nullptr);
    pam_pv_k<<<dim3(400), 1024, 0, stream>>>(Pbuf, buf0, fS, fT, gpam, t);
    gram_mfma_k<<<dim3(16, 25), 256, 0, stream>>>(Pbuf, (size_t)1048576, (size_t)65536,
                                                  G + 512 + t * 6400);
  }
  cka_pair_k<<<dim3(26), 256, 0, stream>>>(G, losses);
  cka_combine_k<<<dim3(1), 64, 0, stream>>>(losses, out);
}